// Round 6
// baseline (464.784 us; speedup 1.0000x reference)
//
#include <hip/hip_runtime.h>
#include <hip/hip_bf16.h>
#include <float.h>
#include <limits.h>

// Problem constants (fixed by reference setup_inputs)
#define BATCH 8
#define NN    4096
#define CC    256
#define KNN_K 4
#define NKE   (NN * KNN_K)

// R16 post-mortem: NJ 64->32 halved LDS reads (bank-conflict counter halved
// exactly, 1.68e7->8.46e6) but dur 233->328us: doubling the chunk count
// doubled barrier/drain overhead and shrank per-chunk phases below what
// hides the fixed costs. LDS *traffic* and *chunk count* were confounded.
// R17: isolate (a) from (b): keep NJ=64, 128 barriers, full-length phases —
// but partition the 64x64 chunk 2x2 among waves (wr=w&1 rows, wc=w>>1 cols).
// Each wave holds TWO A m-tiles in regs; each B-frag ds_read_b128 feeds TWO
// MFMAs. Per wave/chunk: 16 reads (was 32), 32 MFMAs (same), 16 inserts
// (same), same staging/barriers. All numerics identical to the proven R11
// formulation (acc-init 0, +2.0f in pack, predicated self-exclusion, plain
// umax/umin insert, depth-6 lists — union-containment exact). Lists 4->8
// per lane; rescore 12 cands/row/half (R16 epilogue, correctness-proven).
// Register watch: ~170 live at the 3-waves/EU cap; spill tripwire =
// WRITE_SIZE ballooning (R12 signature).
#define MTI  64    // i-rows per block
#define NJ   64    // j-chunk cols
#define NM6  6     // per-lane/merged top-k depth
#define NCND 12    // rescored candidates per row per j-half (2 wc x 6)
#define BROW 264   // B-LDS ushort stride (256 + 8 pad) = 528 B

typedef __attribute__((ext_vector_type(8))) short  bf16x8;
typedef __attribute__((ext_vector_type(4))) float  f32x4;

// fp32 -> bf16 round-to-nearest-even (inputs finite)
__device__ __forceinline__ short f2bf(float f) {
    unsigned u = __float_as_uint(f);
    return (short)((u + 0x7FFFu + ((u >> 16) & 1u)) >> 16);
}

__device__ __forceinline__ unsigned umin32(unsigned a, unsigned b) { return a < b ? a : b; }
__device__ __forceinline__ unsigned umax32(unsigned a, unsigned b) { return a > b ? a : b; }

// branchless sorted-desc insert: t'[s] = max(t[s], min(t[s-1], k)); t'[0]=max(t[0],k)
__device__ __forceinline__ void pk_ins6(unsigned k, unsigned (&t)[NM6]) {
    #pragma unroll
    for (int s = NM6 - 1; s > 0; --s) t[s] = umax32(t[s], umin32(t[s - 1], k));
    t[0] = umax32(t[0], k);
}

// final-selection predicate matching jax.lax.top_k: value desc, ties -> smaller j
__device__ __forceinline__ bool knn_better(float v, int j, float v2, int j2) {
    return (v > v2) || (v == v2 && j < j2);
}
__device__ __forceinline__ void knn_insert4(float v, int j, float (&tv)[4], int (&tj)[4]) {
    if (knn_better(v, j, tv[3], tj[3])) {
        tv[3] = v; tj[3] = j;
        #pragma unroll
        for (int s = 3; s > 0; --s) {
            if (knn_better(tv[s], tj[s], tv[s - 1], tj[s - 1])) {
                float fv = tv[s]; tv[s] = tv[s - 1]; tv[s - 1] = fv;
                int   fj = tj[s]; tj[s] = tj[s - 1]; tj[s - 1] = fj;
            }
        }
    }
}

// ---------------------------------------------------------------------------
// Kernel 1: per-row inv-norm (+ optional normalized bf16 Xn to ws).
// ---------------------------------------------------------------------------
__global__ void knn_prep_kernel(const float* __restrict__ x, float* __restrict__ invn,
                                ushort* __restrict__ xn, int write_bf16) {
    const int row  = blockIdx.x * 4 + (threadIdx.x >> 6);
    const int lane = threadIdx.x & 63;
    const float4 v = *(const float4*)(x + (size_t)row * CC + lane * 4);
    float ss = v.x * v.x + v.y * v.y + v.z * v.z + v.w * v.w;
    #pragma unroll
    for (int off = 32; off > 0; off >>= 1) ss += __shfl_down(ss, off, 64);
    const float inv = 1.0f / sqrtf(__shfl(ss, 0, 64));
    if (lane == 0) invn[row] = inv;
    if (write_bf16) {
        short4 s4;
        s4.x = f2bf(v.x * inv); s4.y = f2bf(v.y * inv);
        s4.z = f2bf(v.z * inv); s4.w = f2bf(v.w * inv);
        *(short4*)(xn + (size_t)row * CC + lane * 4) = s4;
    }
}

// ---------------------------------------------------------------------------
// Kernel 2: 64 i-rows/block vs a j-range (half or full). Wave (wr,wc) owns
// rows [i0+wr*32,+32) x chunk-cols [wc*32,+32). Per 64-col chunk:
//   barA | pregs->Bsh | barB | issue next loads | 8x(2 ds_read + 4 MFMA) | inserts
// Epilogue: shfl-butterfly (16 lm-lanes) -> per-(row,wc) packed top-6 ->
// in-kernel fp32 rescore (EXACT sequential-fmaf chain), 12 cands/row/half.
// Split mode writes scored (val,j) pairs; full mode selects top-4 of 12.
// ---------------------------------------------------------------------------
template<bool FROM_BF16>
__global__ __launch_bounds__(256, 3) void knn_main_kernel(
        const float* __restrict__ x, const float* __restrict__ invn,
        const ushort* __restrict__ xn, float* __restrict__ out,
        float* __restrict__ sval, int* __restrict__ sjid, int nh2) {
    __shared__ __align__(16) ushort Bsh[NJ * BROW];   // 33792 B (only LDS)

    const int tid = threadIdx.x;
    const int b   = blockIdx.x & 7;          // batch -> XCD pinning
    const int t   = blockIdx.x >> 3;
    const int it   = nh2 ? (t >> 1) : t;     // i-tile 0..63
    const int half = nh2 ? (t & 1)  : 0;     // j-half
    const int i0   = it * MTI;
    const int jbase = half * (NN / 2);
    const int nch   = nh2 ? (NN / NJ / 2) : (NN / NJ);   // 32 or 64

    const float*  xb   = x    + (size_t)b * NN * CC;
    const ushort* xnb  = xn   + (size_t)b * NN * CC;
    const float*  invb = invn + (size_t)b * NN;

    const int w  = tid >> 6;                 // wave 0..3
    const int wr = w & 1;                    // row-half of block (32 rows)
    const int wc = w >> 1;                   // col-half of chunk (32 cols)
    const int l  = tid & 63;
    const int lm = l & 15;                   // MFMA m/n lane
    const int q  = l >> 4;                   // quad 0..3

    // ---- A-frags in registers: 2 m-tiles x 8 kt ----
    bf16x8 afrag[2][8];
    #pragma unroll
    for (int mi = 0; mi < 2; ++mi) {
        const int gi = i0 + wr * 32 + mi * 16 + lm;
        if (FROM_BF16) {
            #pragma unroll
            for (int kt = 0; kt < 8; ++kt)
                afrag[mi][kt] = *(const bf16x8*)(xnb + (size_t)gi * CC + kt * 32 + q * 8);
        } else {
            const float vi = invb[gi];
            #pragma unroll
            for (int kt = 0; kt < 8; ++kt) {
                const float* src = xb + (size_t)gi * CC + kt * 32 + q * 8;
                const float4 f0 = *(const float4*)(src);
                const float4 f1 = *(const float4*)(src + 4);
                bf16x8 a;
                a[0] = f2bf(f0.x * vi); a[1] = f2bf(f0.y * vi);
                a[2] = f2bf(f0.z * vi); a[3] = f2bf(f0.w * vi);
                a[4] = f2bf(f1.x * vi); a[5] = f2bf(f1.y * vi);
                a[6] = f2bf(f1.z * vi); a[7] = f2bf(f1.w * vi);
                afrag[mi][kt] = a;
            }
        }
    }

    // per-lane packed top-6; list (mi*4+r) = row i0+wr*32+mi*16+q*4+r over
    // this wave's wc col-window. Depth 6 exact (union-containment).
    unsigned cl[8][NM6];
    #pragma unroll
    for (int r = 0; r < 8; ++r)
        #pragma unroll
        for (int s = 0; s < NM6; ++s) cl[r][s] = 0u;

    // staging ids: 16B granule; rows s_r0+8*lp, 32 granules/row (as R11)
    const int s_gc = tid & 31;
    const int s_r0 = tid >> 5;
    bf16x8 pregs[8];
    if (FROM_BF16) {
        #pragma unroll
        for (int lp = 0; lp < 8; ++lp)
            pregs[lp] = *(const bf16x8*)(xnb + (size_t)(jbase + s_r0 + 8 * lp) * CC + s_gc * 8);
    }

    for (int jt = 0; jt < nch; ++jt) {
        const int j0 = jbase + jt * NJ;
        __syncthreads();                      // (A) prior kt-loop readers done
        if (FROM_BF16) {
            #pragma unroll
            for (int lp = 0; lp < 8; ++lp)
                *(bf16x8*)(Bsh + (s_r0 + 8 * lp) * BROW + s_gc * 8) = pregs[lp];
        } else {
            #pragma unroll
            for (int lp = 0; lp < 16; ++lp) {
                const int u2 = tid + 256 * lp;
                const int row = u2 >> 6, c4 = u2 & 63;
                const float sc = invb[j0 + row];
                const float4 v = *(const float4*)(xb + (size_t)(j0 + row) * CC + c4 * 4);
                short4 s4;
                s4.x = f2bf(v.x * sc); s4.y = f2bf(v.y * sc);
                s4.z = f2bf(v.z * sc); s4.w = f2bf(v.w * sc);
                *(short4*)(Bsh + row * BROW + c4 * 4) = s4;
            }
        }
        __syncthreads();                      // (B) Bsh ready
        // issue NEXT chunk's loads AFTER the barrier (stay in flight through
        // MFMA+insert)
        if (FROM_BF16 && jt + 1 < nch) {
            const int jn = jbase + (jt + 1) * NJ;
            #pragma unroll
            for (int lp = 0; lp < 8; ++lp)
                pregs[lp] = *(const bf16x8*)(xnb + (size_t)(jn + s_r0 + 8 * lp) * CC + s_gc * 8);
        }

        f32x4 acc[2][2];
        #pragma unroll
        for (int mi = 0; mi < 2; ++mi)
            #pragma unroll
            for (int ct = 0; ct < 2; ++ct) acc[mi][ct] = (f32x4){0.f, 0.f, 0.f, 0.f};
        #pragma unroll
        for (int kt = 0; kt < 8; ++kt) {
            #pragma unroll
            for (int ct = 0; ct < 2; ++ct) {
                // ONE B-frag read feeds TWO m-tile MFMAs (reads/MAC halved)
                const bf16x8 bf = *(const bf16x8*)(Bsh + ((wc * 2 + ct) * 16 + lm) * BROW + kt * 32 + q * 8);
                acc[0][ct] = __builtin_amdgcn_mfma_f32_16x16x32_bf16(afrag[0][kt], bf, acc[0][ct], 0, 0, 0);
                acc[1][ct] = __builtin_amdgcn_mfma_f32_16x16x32_bf16(afrag[1][kt], bf, acc[1][ct], 0, 0, 0);
            }
        }

        // ---- pack + branchless insert (R11-proven formulation) ----
        // key = bits(sim+2.0) top-20 (monotone, ULP~3e-5); low-12 = 4095-j
        const bool dchunk = (j0 == i0);
        #pragma unroll
        for (int ct = 0; ct < 2; ++ct) {
            const int cj = (wc * 2 + ct) * 16 + lm;     // col within 64-chunk
            const unsigned ivj = (unsigned)(4095 - (j0 + cj));
            #pragma unroll
            for (int mi = 0; mi < 2; ++mi) {
                #pragma unroll
                for (int r = 0; r < 4; ++r) {
                    unsigned pk = (__float_as_uint(acc[mi][ct][r] + 2.0f) & 0xFFFFF000u) | ivj;
                    if (dchunk && cj == (wr * 32 + mi * 16 + q * 4 + r)) pk = 0u;  // self
                    pk_ins6(pk, cl[mi * 4 + r]);
                }
            }
        }
    }

    // ---- butterfly merge across the 16 lm-lanes, in place on cl ----
    #pragma unroll
    for (int m = 1; m <= 8; m <<= 1) {
        #pragma unroll
        for (int r = 0; r < 8; ++r) {
            unsigned pin[NM6];
            #pragma unroll
            for (int s = 0; s < NM6; ++s)
                pin[s] = (unsigned)__shfl_xor((int)cl[r][s], m, 64);
            #pragma unroll
            for (int s = 0; s < NM6; ++s) pk_ins6(pin[s], cl[r]);
        }
    }

    // ---- stash per-(row,wc) top-6 into LDS (Bsh reuse): [64][2][6] u32 ----
    unsigned* cpk = (unsigned*)Bsh;              // 3072 B
    __syncthreads();                             // all kt-loop readers done
    if (lm == 0) {
        #pragma unroll
        for (int mi = 0; mi < 2; ++mi)
            #pragma unroll
            for (int r = 0; r < 4; ++r) {
                const int rt = wr * 32 + mi * 16 + q * 4 + r;
                #pragma unroll
                for (int s = 0; s < NM6; ++s)
                    cpk[(rt * 2 + wc) * NM6 + s] = cl[mi * 4 + r][s];
            }
    }
    __syncthreads();

    // ---- in-kernel fp32 rescore: EXACT sequential-fmaf chain ----
    // thread t: row = t&63, slot = t>>6; each slot rescores 3 of 12 cands.
    const int rr   = tid & 63;
    const int slot = tid >> 6;
    const int ig   = i0 + rr;
    const float inv_i = invb[ig];
    const float* xi = xb + (size_t)ig * CC;
    float rv[3]; int rj[3];
    #pragma unroll
    for (int u = 0; u < 3; ++u) {
        const int c  = slot * 3 + u;             // 0..11
        const int jc = 4095 - (int)(cpk[rr * NCND + c] & 0xFFFu);
        const float* xj = xb + (size_t)jc * CC;
        float d = 0.f;
        #pragma unroll 16
        for (int k4 = 0; k4 < 64; ++k4) {
            const float4 av = *(const float4*)(xi + k4 * 4);
            const float4 bv = *(const float4*)(xj + k4 * 4);
            d = fmaf(av.x, bv.x, d);
            d = fmaf(av.y, bv.y, d);
            d = fmaf(av.z, bv.z, d);
            d = fmaf(av.w, bv.w, d);
        }
        rv[u] = d * inv_i * invb[jc];
        rj[u] = jc;
    }

    if (nh2) {
        // split mode: write scored pairs; select kernel finishes
        #pragma unroll
        for (int u = 0; u < 3; ++u) {
            const size_t o = ((size_t)(b * NN + ig) * 2 + half) * NCND + (slot * 3 + u);
            sval[o] = rv[u];
            sjid[o] = rj[u];
        }
        return;
    }

    // full-j mode: select top-4 of 12 in-block
    float* cvl = (float*)(Bsh + 4096);           // [64][12] fp32 vals (3072 B)
    #pragma unroll
    for (int u = 0; u < 3; ++u) cvl[rr * NCND + (slot * 3 + u)] = rv[u];
    __syncthreads();
    if (tid < MTI) {
        const int r = tid, ig2 = i0 + r;
        float fv[4]; int fj[4];
        #pragma unroll
        for (int s = 0; s < 4; ++s) { fv[s] = -INFINITY; fj[s] = INT_MAX; }
        for (int c = 0; c < NCND; ++c) {
            const int jc = 4095 - (int)(cpk[r * NCND + c] & 0xFFFu);
            knn_insert4(cvl[r * NCND + c], jc, fv, fj);
        }
        float* o_src = out + (size_t)b * 2 * NKE;
        float* o_tgt = o_src + NKE;
        float* o_w   = out + (size_t)BATCH * 2 * NKE + (size_t)b * NKE;
        #pragma unroll
        for (int s = 0; s < 4; ++s) {
            o_src[ig2 * KNN_K + s] = (float)ig2;
            o_tgt[ig2 * KNN_K + s] = (float)fj[s];
            o_w[ig2 * KNN_K + s]   = fv[s];
        }
    }
}

// ---------------------------------------------------------------------------
// Kernel 3 (split mode): top-4 of 24 pre-scored (val,j) pairs per row.
// ---------------------------------------------------------------------------
__global__ __launch_bounds__(256) void knn_select_kernel(
        const float* __restrict__ sval, const int* __restrict__ sjid,
        float* __restrict__ out) {
    const int row_g = blockIdx.x * 256 + threadIdx.x;   // 0..32767
    const int bb = row_g >> 12, ig = row_g & (NN - 1);
    float fv[4]; int fj[4];
    #pragma unroll
    for (int s = 0; s < 4; ++s) { fv[s] = -INFINITY; fj[s] = INT_MAX; }
    const size_t base = (size_t)row_g * 2 * NCND;
    for (int c = 0; c < 2 * NCND; ++c)
        knn_insert4(sval[base + c], sjid[base + c], fv, fj);
    float* o_src = out + (size_t)bb * 2 * NKE;
    float* o_tgt = o_src + NKE;
    float* o_w   = out + (size_t)BATCH * 2 * NKE + (size_t)bb * NKE;
    #pragma unroll
    for (int s = 0; s < 4; ++s) {
        o_src[ig * KNN_K + s] = (float)ig;
        o_tgt[ig * KNN_K + s] = (float)fj[s];
        o_w[ig * KNN_K + s]   = fv[s];
    }
}

extern "C" void kernel_launch(void* const* d_in, const int* in_sizes, int n_in,
                              void* d_out, int out_size, void* d_ws, size_t ws_size,
                              hipStream_t stream) {
    const float* x    = (const float*)d_in[0];
    float*       out  = (float*)d_out;
    float*       invn = (float*)d_ws;                                   // 128 KB
    ushort*      xn   = (ushort*)((char*)d_ws + 131072);                // 16.78 MB
    char*        p2   = (char*)d_ws + 131072 + (size_t)BATCH * NN * CC * sizeof(ushort);
    float*       sval = (float*)p2;                                     // 3.15 MB
    int*         sjid = (int*)(p2 + (size_t)BATCH * NN * 2 * NCND * sizeof(float));
    const size_t need_xn  = 131072 + (size_t)BATCH * NN * CC * sizeof(ushort);
    const size_t need_all = need_xn + (size_t)BATCH * NN * 2 * NCND * 8;

    if (ws_size >= need_all) {
        knn_prep_kernel<<<(BATCH * NN) / 4, 256, 0, stream>>>(x, invn, xn, 1);
        knn_main_kernel<true><<<BATCH * (NN / MTI) * 2, 256, 0, stream>>>(x, invn, xn, out, sval, sjid, 1);
        knn_select_kernel<<<(BATCH * NN) / 256, 256, 0, stream>>>(sval, sjid, out);
    } else if (ws_size >= need_xn) {
        knn_prep_kernel<<<(BATCH * NN) / 4, 256, 0, stream>>>(x, invn, xn, 1);
        knn_main_kernel<true><<<BATCH * (NN / MTI), 256, 0, stream>>>(x, invn, xn, out, nullptr, nullptr, 0);
    } else {
        knn_prep_kernel<<<(BATCH * NN) / 4, 256, 0, stream>>>(x, invn, xn, 0);
        knn_main_kernel<false><<<BATCH * (NN / MTI), 256, 0, stream>>>(x, invn, xn, out, nullptr, nullptr, 0);
    }
}

// Round 7
// 258.189 us; speedup vs baseline: 1.8002x; 1.8002x over previous
//
#include <hip/hip_runtime.h>
#include <hip/hip_bf16.h>
#include <float.h>
#include <limits.h>

// Problem constants (fixed by reference setup_inputs)
#define BATCH 8
#define NN    4096
#define CC    256
#define KNN_K 4
#define NKE   (NN * KNN_K)

// R18: byte-exact re-anchor on the harness-verified 256.4us artifact (R11).
// Session evidence R12-R17: every deviation regressed — register cliffs
// (R13/R17 spill: WRITE_SIZE 6.7MB -> 1.16GB/87MB), codegen-noise VALU
// rewrites (R14/R15: VALUBusy*dur invariant), barrier-count doubling (R16).
// This kernel sits at a fragile optimum: VGPR 64, 3 blocks/CU, prefetch
// fully overlapped. Re-establish + confirm reproducibility before any
// further single-variable experiment (candidate: global_load_lds staging).
#define MTI  64
#define NJ   64
#define NC8  8     // per-lane packed top-k during scan
#define NM6  6     // per-(row,half) merged top-k, rescored in-kernel
#define BROW 264   // B-LDS ushort stride (256 + 8 pad) = 528 B

typedef __attribute__((ext_vector_type(8))) short  bf16x8;
typedef __attribute__((ext_vector_type(4))) float  f32x4;

// fp32 -> bf16 round-to-nearest-even (inputs finite)
__device__ __forceinline__ short f2bf(float f) {
    unsigned u = __float_as_uint(f);
    return (short)((u + 0x7FFFu + ((u >> 16) & 1u)) >> 16);
}

__device__ __forceinline__ unsigned umin32(unsigned a, unsigned b) { return a < b ? a : b; }
__device__ __forceinline__ unsigned umax32(unsigned a, unsigned b) { return a > b ? a : b; }

// branchless sorted-desc insert: t'[s] = max(t[s], min(t[s-1], k)); t'[0]=max(t[0],k)
__device__ __forceinline__ void pk_ins8(unsigned k, unsigned (&t)[NC8]) {
    #pragma unroll
    for (int s = NC8 - 1; s > 0; --s) t[s] = umax32(t[s], umin32(t[s - 1], k));
    t[0] = umax32(t[0], k);
}
__device__ __forceinline__ void pk_ins6(unsigned k, unsigned (&t)[NM6]) {
    #pragma unroll
    for (int s = NM6 - 1; s > 0; --s) t[s] = umax32(t[s], umin32(t[s - 1], k));
    t[0] = umax32(t[0], k);
}

// final-selection predicate matching jax.lax.top_k: value desc, ties -> smaller j
__device__ __forceinline__ bool knn_better(float v, int j, float v2, int j2) {
    return (v > v2) || (v == v2 && j < j2);
}
__device__ __forceinline__ void knn_insert4(float v, int j, float (&tv)[4], int (&tj)[4]) {
    if (knn_better(v, j, tv[3], tj[3])) {
        tv[3] = v; tj[3] = j;
        #pragma unroll
        for (int s = 3; s > 0; --s) {
            if (knn_better(tv[s], tj[s], tv[s - 1], tj[s - 1])) {
                float fv = tv[s]; tv[s] = tv[s - 1]; tv[s - 1] = fv;
                int   fj = tj[s]; tj[s] = tj[s - 1]; tj[s - 1] = fj;
            }
        }
    }
}

// ---------------------------------------------------------------------------
// Kernel 1: per-row inv-norm (+ optional normalized bf16 Xn to ws).
// ---------------------------------------------------------------------------
__global__ void knn_prep_kernel(const float* __restrict__ x, float* __restrict__ invn,
                                ushort* __restrict__ xn, int write_bf16) {
    const int row  = blockIdx.x * 4 + (threadIdx.x >> 6);
    const int lane = threadIdx.x & 63;
    const float4 v = *(const float4*)(x + (size_t)row * CC + lane * 4);
    float ss = v.x * v.x + v.y * v.y + v.z * v.z + v.w * v.w;
    #pragma unroll
    for (int off = 32; off > 0; off >>= 1) ss += __shfl_down(ss, off, 64);
    const float inv = 1.0f / sqrtf(__shfl(ss, 0, 64));
    if (lane == 0) invn[row] = inv;
    if (write_bf16) {
        short4 s4;
        s4.x = f2bf(v.x * inv); s4.y = f2bf(v.y * inv);
        s4.z = f2bf(v.z * inv); s4.w = f2bf(v.w * inv);
        *(short4*)(xn + (size_t)row * CC + lane * 4) = s4;
    }
}

// ---------------------------------------------------------------------------
// Kernel 2: 64 i-rows/block vs a j-range (half or full). Per 64-col chunk:
//   barA | pregs->Bsh | barB | issue next loads | 32 MFMA | packed inserts
// Epilogue: shfl-butterfly (16 lm-lanes) -> per-row packed top-6 -> in-kernel
// fp32 rescore (EXACT R1-R5 sequential-fmaf chain). Split mode writes scored
// (val,j) pairs to ws; full mode selects top-4 and writes outputs directly.
// ---------------------------------------------------------------------------
template<bool FROM_BF16>
__global__ __launch_bounds__(256, 3) void knn_main_kernel(
        const float* __restrict__ x, const float* __restrict__ invn,
        const ushort* __restrict__ xn, float* __restrict__ out,
        float* __restrict__ sval, int* __restrict__ sjid, int nh2) {
    __shared__ __align__(16) ushort Bsh[NJ * BROW];   // 33792 B (only LDS)

    const int tid = threadIdx.x;
    const int b   = blockIdx.x & 7;          // batch -> XCD pinning
    const int t   = blockIdx.x >> 3;
    const int it   = nh2 ? (t >> 1) : t;     // i-tile 0..63
    const int half = nh2 ? (t & 1)  : 0;     // j-half
    const int i0   = it * MTI;
    const int jbase = half * (NN / 2);
    const int nch   = nh2 ? (NN / NJ / 2) : (NN / NJ);

    const float*  xb   = x    + (size_t)b * NN * CC;
    const ushort* xnb  = xn   + (size_t)b * NN * CC;
    const float*  invb = invn + (size_t)b * NN;

    const int w  = tid >> 6;                 // wave 0..3 (rows w*16..w*16+15)
    const int l  = tid & 63;
    const int lm = l & 15;                   // MFMA m/n lane
    const int q  = l >> 4;                   // quad 0..3

    // ---- A-frags in registers (32 VGPRs); A[m=lane&15][k=quad*8+j] ----
    bf16x8 afrag[8];
    const int gi = i0 + w * 16 + lm;
    if (FROM_BF16) {
        #pragma unroll
        for (int kt = 0; kt < 8; ++kt)
            afrag[kt] = *(const bf16x8*)(xnb + (size_t)gi * CC + kt * 32 + q * 8);
    } else {
        const float vi = invb[gi];
        #pragma unroll
        for (int kt = 0; kt < 8; ++kt) {
            const float* src = xb + (size_t)gi * CC + kt * 32 + q * 8;
            const float4 f0 = *(const float4*)(src);
            const float4 f1 = *(const float4*)(src + 4);
            bf16x8 a;
            a[0] = f2bf(f0.x * vi); a[1] = f2bf(f0.y * vi);
            a[2] = f2bf(f0.z * vi); a[3] = f2bf(f0.w * vi);
            a[4] = f2bf(f1.x * vi); a[5] = f2bf(f1.y * vi);
            a[6] = f2bf(f1.z * vi); a[7] = f2bf(f1.w * vi);
            afrag[kt] = a;
        }
    }

    // per-lane packed top-8, one list per owned row (reg 0..3 = rows q*4+reg)
    unsigned cl[4][NC8];
    #pragma unroll
    for (int r = 0; r < 4; ++r)
        #pragma unroll
        for (int s = 0; s < NC8; ++s) cl[r][s] = 0u;

    // staging ids: 16B granule; rows s_r0+8*lp, 32 granules/row
    const int s_gc = tid & 31;
    const int s_r0 = tid >> 5;
    bf16x8 pregs[8];
    if (FROM_BF16) {
        #pragma unroll
        for (int lp = 0; lp < 8; ++lp)
            pregs[lp] = *(const bf16x8*)(xnb + (size_t)(jbase + s_r0 + 8 * lp) * CC + s_gc * 8);
    }

    for (int jt = 0; jt < nch; ++jt) {
        const int j0 = jbase + jt * NJ;
        __syncthreads();                      // (A) prior kt-loop readers done
        if (FROM_BF16) {
            #pragma unroll
            for (int lp = 0; lp < 8; ++lp)
                *(bf16x8*)(Bsh + (s_r0 + 8 * lp) * BROW + s_gc * 8) = pregs[lp];
        } else {
            #pragma unroll
            for (int lp = 0; lp < 16; ++lp) {
                const int u2 = tid + 256 * lp;
                const int row = u2 >> 6, c4 = u2 & 63;
                const float sc = invb[j0 + row];
                const float4 v = *(const float4*)(xb + (size_t)(j0 + row) * CC + c4 * 4);
                short4 s4;
                s4.x = f2bf(v.x * sc); s4.y = f2bf(v.y * sc);
                s4.z = f2bf(v.z * sc); s4.w = f2bf(v.w * sc);
                *(short4*)(Bsh + row * BROW + c4 * 4) = s4;
            }
        }
        __syncthreads();                      // (B) Bsh ready
        // issue NEXT chunk's loads AFTER the barrier (stay in flight through
        // MFMA+insert; s_barrier would have forced vmcnt(0))
        if (FROM_BF16 && jt + 1 < nch) {
            const int jn = jbase + (jt + 1) * NJ;
            #pragma unroll
            for (int lp = 0; lp < 8; ++lp)
                pregs[lp] = *(const bf16x8*)(xnb + (size_t)(jn + s_r0 + 8 * lp) * CC + s_gc * 8);
        }

        f32x4 acc[4];
        #pragma unroll
        for (int ct = 0; ct < 4; ++ct) acc[ct] = (f32x4){0.f, 0.f, 0.f, 0.f};
        #pragma unroll
        for (int kt = 0; kt < 8; ++kt) {
            #pragma unroll
            for (int ct = 0; ct < 4; ++ct) {
                const bf16x8 bf = *(const bf16x8*)(Bsh + (ct * 16 + lm) * BROW + kt * 32 + q * 8);
                acc[ct] = __builtin_amdgcn_mfma_f32_16x16x32_bf16(afrag[kt], bf, acc[ct], 0, 0, 0);
            }
        }

        // ---- pack + branchless insert (no LDS, no divergence) ----
        // key = bits(sim+2.0) top-20 (monotone, ULP~3e-5); low-12 = 4095-j
        const bool dchunk = (j0 == i0);
        #pragma unroll
        for (int ct = 0; ct < 4; ++ct) {
            const int jg  = j0 + ct * 16 + lm;
            const unsigned ivj = (unsigned)(4095 - jg);
            #pragma unroll
            for (int r = 0; r < 4; ++r) {
                unsigned pk = (__float_as_uint(acc[ct][r] + 2.0f) & 0xFFFFF000u) | ivj;
                if (dchunk && (w * 16 + q * 4 + r) == (ct * 16 + lm)) pk = 0u;  // self
                pk_ins8(pk, cl[r]);
            }
        }
    }

    // ---- butterfly merge across the 16 lm-lanes -> per-row packed top-6 ----
    unsigned tm[4][NM6];
    #pragma unroll
    for (int r = 0; r < 4; ++r)
        #pragma unroll
        for (int s = 0; s < NM6; ++s) tm[r][s] = cl[r][s];   // top-6 of sorted top-8
    #pragma unroll
    for (int m = 1; m <= 8; m <<= 1) {
        #pragma unroll
        for (int r = 0; r < 4; ++r) {
            unsigned pin[NM6];
            #pragma unroll
            for (int s = 0; s < NM6; ++s)
                pin[s] = (unsigned)__shfl_xor((int)tm[r][s], m, 64);
            #pragma unroll
            for (int s = 0; s < NM6; ++s) pk_ins6(pin[s], tm[r]);
        }
    }

    // ---- stash per-row top-6 into LDS (Bsh reuse) for the rescore phase ----
    unsigned* cpk = (unsigned*)Bsh;              // [64][6] packed (1.5 KB)
    __syncthreads();                             // all kt-loop readers done
    if (lm == 0) {
        #pragma unroll
        for (int r = 0; r < 4; ++r) {
            const int rt = w * 16 + q * 4 + r;
            #pragma unroll
            for (int s = 0; s < NM6; ++s) cpk[rt * NM6 + s] = tm[r][s];
        }
    }
    __syncthreads();

    // ---- in-kernel fp32 rescore: EXACT R1-R5 sequential-fmaf chain ----
    // thread t: row = t&63, slot = t>>6; slots 0/1 do 2 cands, 2/3 do 1.
    const int rr   = tid & 63;
    const int slot = tid >> 6;
    const int ig   = i0 + rr;
    const float inv_i = invb[ig];
    const float* xi = xb + (size_t)ig * CC;
    const int ncand = (slot < 2) ? 2 : 1;
    const int cbase = (slot < 2) ? slot * 2 : 2 + slot;   // {0,1},{2,3},{4},{5}
    float rv[2]; int rj[2];
    for (int u = 0; u < ncand; ++u) {
        const int c  = cbase + u;
        const int jc = 4095 - (int)(cpk[rr * NM6 + c] & 0xFFFu);
        const float* xj = xb + (size_t)jc * CC;
        float d = 0.f;
        #pragma unroll 16
        for (int k4 = 0; k4 < 64; ++k4) {
            const float4 av = *(const float4*)(xi + k4 * 4);
            const float4 bv = *(const float4*)(xj + k4 * 4);
            d = fmaf(av.x, bv.x, d);
            d = fmaf(av.y, bv.y, d);
            d = fmaf(av.z, bv.z, d);
            d = fmaf(av.w, bv.w, d);
        }
        rv[u] = d * inv_i * invb[jc];
        rj[u] = jc;
    }

    if (nh2) {
        // split mode: write scored pairs; select kernel finishes
        for (int u = 0; u < ncand; ++u) {
            const size_t o = ((size_t)(b * NN + ig) * 2 + half) * NM6 + (cbase + u);
            sval[o] = rv[u];
            sjid[o] = rj[u];
        }
        return;
    }

    // full-j mode: select top-4 of 6 in-block
    float* cvl = (float*)(Bsh + 4096);           // [64][6] fp32 vals
    for (int u = 0; u < ncand; ++u) cvl[rr * NM6 + (cbase + u)] = rv[u];
    __syncthreads();
    if (tid < MTI) {
        const int r = tid, ig2 = i0 + r;
        float fv[4]; int fj[4];
        #pragma unroll
        for (int s = 0; s < 4; ++s) { fv[s] = -INFINITY; fj[s] = INT_MAX; }
        for (int c = 0; c < NM6; ++c) {
            const int jc = 4095 - (int)(cpk[r * NM6 + c] & 0xFFFu);
            knn_insert4(cvl[r * NM6 + c], jc, fv, fj);
        }
        float* o_src = out + (size_t)b * 2 * NKE;
        float* o_tgt = o_src + NKE;
        float* o_w   = out + (size_t)BATCH * 2 * NKE + (size_t)b * NKE;
        #pragma unroll
        for (int s = 0; s < 4; ++s) {
            o_src[ig2 * KNN_K + s] = (float)ig2;
            o_tgt[ig2 * KNN_K + s] = (float)fj[s];
            o_w[ig2 * KNN_K + s]   = fv[s];
        }
    }
}

// ---------------------------------------------------------------------------
// Kernel 3 (split mode): top-4 of 12 pre-scored (val,j) pairs per row. 3MB.
// ---------------------------------------------------------------------------
__global__ __launch_bounds__(256) void knn_select_kernel(
        const float* __restrict__ sval, const int* __restrict__ sjid,
        float* __restrict__ out) {
    const int row_g = blockIdx.x * 256 + threadIdx.x;   // 0..32767
    const int bb = row_g >> 12, ig = row_g & (NN - 1);
    float fv[4]; int fj[4];
    #pragma unroll
    for (int s = 0; s < 4; ++s) { fv[s] = -INFINITY; fj[s] = INT_MAX; }
    const size_t base = (size_t)row_g * 2 * NM6;
    for (int c = 0; c < 2 * NM6; ++c)
        knn_insert4(sval[base + c], sjid[base + c], fv, fj);
    float* o_src = out + (size_t)bb * 2 * NKE;
    float* o_tgt = o_src + NKE;
    float* o_w   = out + (size_t)BATCH * 2 * NKE + (size_t)bb * NKE;
    #pragma unroll
    for (int s = 0; s < 4; ++s) {
        o_src[ig * KNN_K + s] = (float)ig;
        o_tgt[ig * KNN_K + s] = (float)fj[s];
        o_w[ig * KNN_K + s]   = fv[s];
    }
}

extern "C" void kernel_launch(void* const* d_in, const int* in_sizes, int n_in,
                              void* d_out, int out_size, void* d_ws, size_t ws_size,
                              hipStream_t stream) {
    const float* x    = (const float*)d_in[0];
    float*       out  = (float*)d_out;
    float*       invn = (float*)d_ws;                                   // 128 KB
    ushort*      xn   = (ushort*)((char*)d_ws + 131072);                // 16.78 MB
    char*        p2   = (char*)d_ws + 131072 + (size_t)BATCH * NN * CC * sizeof(ushort);
    float*       sval = (float*)p2;                                     // 1.57 MB
    int*         sjid = (int*)(p2 + (size_t)BATCH * NN * 2 * NM6 * sizeof(float));
    const size_t need_xn  = 131072 + (size_t)BATCH * NN * CC * sizeof(ushort);
    const size_t need_all = need_xn + (size_t)BATCH * NN * 2 * NM6 * 8;

    if (ws_size >= need_all) {
        knn_prep_kernel<<<(BATCH * NN) / 4, 256, 0, stream>>>(x, invn, xn, 1);
        knn_main_kernel<true><<<BATCH * MTI * 2, 256, 0, stream>>>(x, invn, xn, out, sval, sjid, 1);
        knn_select_kernel<<<(BATCH * NN) / 256, 256, 0, stream>>>(sval, sjid, out);
    } else if (ws_size >= need_xn) {
        knn_prep_kernel<<<(BATCH * NN) / 4, 256, 0, stream>>>(x, invn, xn, 1);
        knn_main_kernel<true><<<BATCH * MTI, 256, 0, stream>>>(x, invn, xn, out, nullptr, nullptr, 0);
    } else {
        knn_prep_kernel<<<(BATCH * NN) / 4, 256, 0, stream>>>(x, invn, xn, 0);
        knn_main_kernel<false><<<BATCH * MTI, 256, 0, stream>>>(x, invn, xn, out, nullptr, nullptr, 0);
    }
}